// Round 9
// baseline (118.826 us; speedup 1.0000x reference)
//
#include <hip/hip_runtime.h>
#include <hip/hip_bf16.h>

#define T_TOK 256
#define C_DIM 1024
#define H_DIM 2048
#define E_NUM 8

typedef __attribute__((ext_vector_type(4))) float f32x4;
typedef __attribute__((ext_vector_type(8))) short short8;

// workspace layout (bytes)
#define WS_CNT    0
#define WS_LIST   1024
#define WS_XBF    16384                      // 256*1024*2 = 512 KB
#define WS_HBUF   (1u<<20)                   // 1 MB bf16 (expert h)
#define WS_HSBUF  (2u<<20)                   // 1 MB bf16 (shared h)
#define WS_YS     (3u<<20)                   // 1 MB f32 (shared y)

__device__ __forceinline__ ushort f2bf(float f) {
    __hip_bfloat16 h = __float2bfloat16(f);
    return *reinterpret_cast<ushort*>(&h);
}

__device__ __forceinline__ ushort4 f2bf4(float4 v) {
    ushort4 r; r.x = f2bf(v.x); r.y = f2bf(v.y); r.z = f2bf(v.z); r.w = f2bf(v.w);
    return r;
}

// async global->LDS DMA, 16B/lane. LDS dest = wave-uniform base + lane*16.
__device__ __forceinline__ void gload16(const void* g, void* l) {
    __builtin_amdgcn_global_load_lds((const __attribute__((address_space(1))) void*)g,
                                     (__attribute__((address_space(3))) void*)l, 16, 0, 0);
}

#define MFMA(a, b, c) __builtin_amdgcn_mfma_f32_16x16x32_bf16((a), (b), (c), 0, 0, 0)

// router + x->bf16 prep fused. 1 block per token.
__global__ __launch_bounds__(256) void router_kernel(
    const float* __restrict__ x, const float* __restrict__ router,
    int* __restrict__ cnt, int* __restrict__ list, ushort* __restrict__ xbf)
{
    const int t = blockIdx.x;
    const int tid = threadIdx.x;
    float4 xv = reinterpret_cast<const float4*>(x + (size_t)t * C_DIM)[tid];
    ushort4 xb = f2bf4(xv);
    *reinterpret_cast<ushort4*>(xbf + (size_t)t * C_DIM + tid * 4) = xb;

    float p[E_NUM];
#pragma unroll
    for (int e = 0; e < E_NUM; e++) {
        float4 rv = reinterpret_cast<const float4*>(router + (size_t)e * C_DIM)[tid];
        p[e] = xv.x * rv.x + xv.y * rv.y + xv.z * rv.z + xv.w * rv.w;
    }
#pragma unroll
    for (int e = 0; e < E_NUM; e++) {
#pragma unroll
        for (int off = 32; off >= 1; off >>= 1)
            p[e] += __shfl_down(p[e], off, 64);
    }
    __shared__ float red[E_NUM][4];
    const int lane = tid & 63, wv = tid >> 6;
    if (lane == 0) {
#pragma unroll
        for (int e = 0; e < E_NUM; e++) red[e][wv] = p[e];
    }
    __syncthreads();
    if (tid == 0) {
        float best = -3.4e38f; int bi = 0;
#pragma unroll
        for (int e = 0; e < E_NUM; e++) {
            float v = red[e][0] + red[e][1] + red[e][2] + red[e][3];
            if (v > best) { best = v; bi = e; }
        }
        int pos = atomicAdd(&cnt[bi], 1);
        list[bi * T_TOK + pos] = t;
    }
}

// ug: panel of 16 h-rows, FULL K=1024 staged once (bf16, swizzled) from
// page-contiguous 1KB-per-instruction reads. M-loop over 16-token tiles,
// x double-buffered via gload_lds. 4 waves split K; LDS reduce + silu.
// grid (9 [8=shared], H/16=128), block 256.
__global__ __launch_bounds__(256) void ug_mfma(
    const ushort* __restrict__ xbf, const float* __restrict__ up, const float* __restrict__ gate,
    const float* __restrict__ w_up_s, const float* __restrict__ w_gate_s,
    const int* __restrict__ cnt, const int* __restrict__ list,
    ushort* __restrict__ hbuf, ushort* __restrict__ hsbuf)
{
    const int e = blockIdx.x, by = blockIdx.y;
    const bool sh = (e == E_NUM);
    const int n = sh ? T_TOK : cnt[e];
    if (n == 0) return;
    const int mtn = (n + 15) >> 4;

    const int tid = threadIdx.x, lane = tid & 63, wv = tid >> 6;
    const int lc = lane & 15, kg = lane >> 4;

    __shared__ ushort Wu[16 * 1024];     // 32 KB  [16 rows][1024 bf16] swizzled
    __shared__ ushort Wg[16 * 1024];     // 32 KB
    __shared__ ushort X[2][16 * 1024];   // 64 KB  x tiles (double buffer)
    __shared__ f32x4 redU[4][64];        // 4 KB
    __shared__ f32x4 redG[4][64];        // 4 KB
    __shared__ int toksLds[4][16];

    const int h0 = by * 16;
    const float* __restrict__ ubase = (sh ? w_up_s   : up   + (size_t)e * H_DIM * C_DIM) + (size_t)h0 * C_DIM;
    const float* __restrict__ gbase = (sh ? w_gate_s : gate + (size_t)e * H_DIM * C_DIM) + (size_t)h0 * C_DIM;

#define LOAD_TOKS(slot, m) do { if (tid < 16) { \
        int tt_ = (m) * 16 + tid; \
        toksLds[slot][tid] = (tt_ < n) ? (sh ? tt_ : list[e * T_TOK + tt_]) : -1; } } while (0)

    // x tile stage: 32 instrs/block, 8 per wave; 1 row = 2 instrs of 1KB.
#define STAGE_X(nb, st) do { \
        _Pragma("unroll") \
        for (int j = 0; j < 8; j++) { \
            int li = wv * 8 + j; \
            int row = li >> 1; \
            int unit = ((li & 1) << 6) + lane; \
            int su = (unit & ~7) | ((unit & 7) ^ (row & 7)); \
            int tok = toksLds[st][row]; if (tok < 0) tok = 0; \
            gload16(xbf + (size_t)tok * C_DIM + su * 8, (void*)&X[nb][li * 512]); \
        } } while (0)

    // weight write: row, 1KB-chunk c, lane's float4 -> swizzled bf16
#define WWRITE(WL, row, c, v) do { \
        int unit_ = ((c) << 5) + (lane >> 1); \
        int swu_ = (unit_ & ~7) | ((unit_ & 7) ^ ((row) & 7)); \
        *reinterpret_cast<ushort4*>(&WL[(row) * 1024 + swu_ * 8 + (lane & 1) * 4]) = f2bf4(v); \
    } while (0)

    // ---- prologue ----
    LOAD_TOKS(0, 0);
    __syncthreads();
    STAGE_X(0, 0);
    if (mtn > 1) LOAD_TOKS(1, 1);

    // stage weights: wave owns rows [wv*4, wv*4+4); 16 loads per matrix,
    // each 1KB contiguous of one row. All 32 in flight, then write.
    {
        const int r0 = wv * 4;
        float4 wuv[16], wgv[16];
#pragma unroll
        for (int i = 0; i < 16; i++) {
            int rr = i >> 2, c = i & 3;
            wuv[i] = *reinterpret_cast<const float4*>(ubase + (size_t)(r0 + rr) * C_DIM + c * 256 + lane * 4);
        }
#pragma unroll
        for (int i = 0; i < 16; i++) {
            int rr = i >> 2, c = i & 3;
            wgv[i] = *reinterpret_cast<const float4*>(gbase + (size_t)(r0 + rr) * C_DIM + c * 256 + lane * 4);
        }
#pragma unroll
        for (int i = 0; i < 16; i++) WWRITE(Wu, r0 + (i >> 2), i & 3, wuv[i]);
#pragma unroll
        for (int i = 0; i < 16; i++) WWRITE(Wg, r0 + (i >> 2), i & 3, wgv[i]);
    }
    __syncthreads();   // weights + X[0] ready (drains vmem + lds)

    ushort* __restrict__ outp = sh ? hsbuf : hbuf;

    // ---- M-loop ----
    for (int mt = 0; mt < mtn; mt++) {
        const int cur = mt & 1;
        if (mt + 1 < mtn) STAGE_X(cur ^ 1, (mt + 1) & 3);

        f32x4 au = {0, 0, 0, 0}, ag = {0, 0, 0, 0};
#pragma unroll
        for (int k8 = 0; k8 < 8; k8++) {
            int ks = wv * 8 + k8;
            int unit = ks * 4 + kg;
            int swa = (unit & ~7) | ((unit & 7) ^ (lc & 7));
            int off = lc * 1024 + swa * 8;
            short8 a  = *reinterpret_cast<const short8*>(&X[cur][off]);
            short8 bu = *reinterpret_cast<const short8*>(&Wu[off]);
            short8 bg = *reinterpret_cast<const short8*>(&Wg[off]);
            au = MFMA(a, bu, au);
            ag = MFMA(a, bg, ag);
        }
        redU[wv][lane] = au;
        redG[wv][lane] = ag;
        if (mt + 2 < mtn) LOAD_TOKS((mt + 2) & 3, mt + 2);
        __syncthreads();   // red + toks ready; X[cur^1] loads drained

        if (wv == 0) {
            f32x4 su = redU[0][lane]; su += redU[1][lane]; su += redU[2][lane]; su += redU[3][lane];
            f32x4 sg = redG[0][lane]; sg += redG[1][lane]; sg += redG[2][lane]; sg += redG[3][lane];
            const int st = mt & 3;
#pragma unroll
            for (int j = 0; j < 4; j++) {
                int row = kg * 4 + j;
                int tok = toksLds[st][row];
                if (tok >= 0) {
                    float g = sg[j], u = su[j];
                    outp[(size_t)tok * H_DIM + h0 + lc] = f2bf(u * (g / (1.f + __expf(-g))));
                }
            }
        }
        __syncthreads();   // wave0 done; red/X reusable
    }
#undef STAGE_X
#undef WWRITE
#undef LOAD_TOKS
}

// down: panel of 16 c-rows, FULL K=2048 staged once (bf16, swizzled).
// M-loop over 16-token h tiles (single buffer). grid (9, C/16=64), block 256.
__global__ __launch_bounds__(256) void down_mfma(
    const float* __restrict__ dwn, const float* __restrict__ w_down_s,
    const ushort* __restrict__ hbuf, const ushort* __restrict__ hsbuf,
    const int* __restrict__ cnt, const int* __restrict__ list,
    float* __restrict__ y, float* __restrict__ yspart)
{
    const int e = blockIdx.x, by = blockIdx.y;
    const bool sh = (e == E_NUM);
    const int n = sh ? T_TOK : cnt[e];
    if (n == 0) return;
    const int mtn = (n + 15) >> 4;

    const int tid = threadIdx.x, lane = tid & 63, wv = tid >> 6;
    const int lc = lane & 15, kg = lane >> 4;

    __shared__ ushort Wd[16 * 2048];     // 64 KB [16 rows][2048 bf16] swizzled
    __shared__ ushort H[16 * 2048];      // 64 KB h tile
    __shared__ f32x4 redD[4][64];        // 4 KB
    __shared__ int toksLds[4][16];

    const int c0 = by * 16;
    const float* __restrict__ dbase = (sh ? w_down_s : dwn + (size_t)e * C_DIM * H_DIM) + (size_t)c0 * H_DIM;
    const ushort* __restrict__ hin = sh ? hsbuf : hbuf;

#define LOAD_TOKS(slot, m) do { if (tid < 16) { \
        int tt_ = (m) * 16 + tid; \
        toksLds[slot][tid] = (tt_ < n) ? (sh ? tt_ : list[e * T_TOK + tt_]) : -1; } } while (0)

    // h tile stage: 64 instrs/block, 16 per wave; 1 row = 4 instrs of 1KB.
#define STAGE_H(st) do { \
        _Pragma("unroll") \
        for (int j = 0; j < 16; j++) { \
            int li = wv * 16 + j; \
            int row = li >> 2; \
            int unit = ((li & 3) << 6) + lane; \
            int su = (unit & ~7) | ((unit & 7) ^ (row & 7)); \
            int tok = toksLds[st][row]; if (tok < 0) tok = 0; \
            gload16(hin + (size_t)tok * H_DIM + su * 8, (void*)&H[li * 512]); \
        } } while (0)

#define WWRITE(row, c, v) do { \
        int unit_ = ((c) << 5) + (lane >> 1); \
        int swu_ = (unit_ & ~7) | ((unit_ & 7) ^ ((row) & 7)); \
        *reinterpret_cast<ushort4*>(&Wd[(row) * 2048 + swu_ * 8 + (lane & 1) * 4]) = f2bf4(v); \
    } while (0)

    // ---- prologue: toks(0) + weights (full K, 32 contiguous 1KB loads/wave)
    LOAD_TOKS(0, 0);
    {
        const int r0 = wv * 4;
        float4 wdv[32];
#pragma unroll
        for (int i = 0; i < 32; i++) {
            int rr = i >> 3, c = i & 7;
            wdv[i] = *reinterpret_cast<const float4*>(dbase + (size_t)(r0 + rr) * H_DIM + c * 256 + lane * 4);
        }
#pragma unroll
        for (int i = 0; i < 32; i++) WWRITE(r0 + (i >> 3), i & 7, wdv[i]);
    }
    __syncthreads();   // toks(0) + Wd ready

    float* __restrict__ outp = sh ? yspart : y;

    // ---- M-loop (H single-buffered) ----
    for (int mt = 0; mt < mtn; mt++) {
        STAGE_H(mt & 3);
        if (mt + 1 < mtn) LOAD_TOKS((mt + 1) & 3, mt + 1);
        __syncthreads();   // H ready (drain)

        f32x4 ac = {0, 0, 0, 0};
#pragma unroll
        for (int k16 = 0; k16 < 16; k16++) {
            int ks = wv * 16 + k16;
            int unit = ks * 4 + kg;
            int swa = (unit & ~7) | ((unit & 7) ^ (lc & 7));
            int off = lc * 2048 + swa * 8;
            short8 a  = *reinterpret_cast<const short8*>(&H[off]);
            short8 bd = *reinterpret_cast<const short8*>(&Wd[off]);
            ac = MFMA(a, bd, ac);
        }
        redD[wv][lane] = ac;
        __syncthreads();   // red ready; H consumed

        if (wv == 0) {
            f32x4 s = redD[0][lane]; s += redD[1][lane]; s += redD[2][lane]; s += redD[3][lane];
            const int st = mt & 3;
#pragma unroll
            for (int j = 0; j < 4; j++) {
                int row = kg * 4 + j;
                int tok = toksLds[st][row];
                if (tok >= 0) outp[(size_t)tok * C_DIM + c0 + lc] = s[j];
            }
        }
        __syncthreads();   // wave0 done; H overwrite safe next iter
    }
#undef STAGE_H
#undef WWRITE
#undef LOAD_TOKS
}

__global__ __launch_bounds__(256) void add_kernel(float* __restrict__ y, const float* __restrict__ ys)
{
    int i = blockIdx.x * 256 + threadIdx.x;
    float4 a = reinterpret_cast<float4*>(y)[i];
    float4 b = reinterpret_cast<const float4*>(ys)[i];
    a.x += b.x; a.y += b.y; a.z += b.z; a.w += b.w;
    reinterpret_cast<float4*>(y)[i] = a;
}

extern "C" void kernel_launch(void* const* d_in, const int* in_sizes, int n_in,
                              void* d_out, int out_size, void* d_ws, size_t ws_size,
                              hipStream_t stream)
{
    const float* x        = (const float*)d_in[0];
    const float* up       = (const float*)d_in[1];
    const float* gate     = (const float*)d_in[2];
    const float* dwn      = (const float*)d_in[3];
    const float* router   = (const float*)d_in[4];
    const float* w_up_s   = (const float*)d_in[5];
    const float* w_gate_s = (const float*)d_in[6];
    const float* w_down_s = (const float*)d_in[7];

    char* ws = (char*)d_ws;
    int* cnt      = (int*)(ws + WS_CNT);
    int* list     = (int*)(ws + WS_LIST);
    ushort* xbf   = (ushort*)(ws + WS_XBF);
    ushort* hbuf  = (ushort*)(ws + WS_HBUF);
    ushort* hsbuf = (ushort*)(ws + WS_HSBUF);
    float* yspart = (float*)(ws + WS_YS);
    float* y = (float*)d_out;

    hipMemsetAsync(cnt, 0, E_NUM * sizeof(int), stream);
    router_kernel<<<T_TOK, 256, 0, stream>>>(x, router, cnt, list, xbf);
    ug_mfma<<<dim3(E_NUM + 1, H_DIM / 16), 256, 0, stream>>>(
        xbf, up, gate, w_up_s, w_gate_s, cnt, list, hbuf, hsbuf);
    down_mfma<<<dim3(E_NUM + 1, C_DIM / 16), 256, 0, stream>>>(
        dwn, w_down_s, hbuf, hsbuf, cnt, list, y, yspart);
    add_kernel<<<(T_TOK * C_DIM / 4) / 256, 256, 0, stream>>>(y, yspart);
}

// Round 10
// 92.566 us; speedup vs baseline: 1.2837x; 1.2837x over previous
//
#include <hip/hip_runtime.h>
#include <hip/hip_bf16.h>

#define T_TOK 256
#define C_DIM 1024
#define H_DIM 2048
#define E_NUM 8

typedef __attribute__((ext_vector_type(4))) float f32x4;
typedef __attribute__((ext_vector_type(8))) short short8;

// workspace layout (bytes)
#define WS_CNT    0
#define WS_LIST   1024
#define WS_XBF    16384                      // 256*1024*2 = 512 KB
#define WS_HBUF   (1u<<20)                   // 1 MB bf16 (expert h)
#define WS_HSBUF  (2u<<20)                   // 1 MB bf16 (shared h)
#define WS_YS     (3u<<20)                   // 1 MB f32 (shared y)

__device__ __forceinline__ ushort f2bf(float f) {
    __hip_bfloat16 h = __float2bfloat16(f);
    return *reinterpret_cast<ushort*>(&h);
}

__device__ __forceinline__ ushort4 f2bf4(float4 v) {
    ushort4 r; r.x = f2bf(v.x); r.y = f2bf(v.y); r.z = f2bf(v.z); r.w = f2bf(v.w);
    return r;
}

// async global->LDS DMA, 16B/lane. LDS dest = wave-uniform base + lane*16.
__device__ __forceinline__ void gload16(const void* g, void* l) {
    __builtin_amdgcn_global_load_lds((const __attribute__((address_space(1))) void*)g,
                                     (__attribute__((address_space(3))) void*)l, 16, 0, 0);
}

#define MFMA(a, b, c) __builtin_amdgcn_mfma_f32_16x16x32_bf16((a), (b), (c), 0, 0, 0)

#define VMWAIT(N) do { asm volatile("s_waitcnt vmcnt(" #N ")" ::: "memory"); \
                       __builtin_amdgcn_sched_barrier(0); } while (0)
#define LGKWAIT() do { asm volatile("s_waitcnt lgkmcnt(0)" ::: "memory"); \
                       __builtin_amdgcn_sched_barrier(0); } while (0)
#define BAR() do { __builtin_amdgcn_s_barrier(); \
                   __builtin_amdgcn_sched_barrier(0); } while (0)

// router + x->bf16 prep fused. 1 block per token.
__global__ __launch_bounds__(256) void router_kernel(
    const float* __restrict__ x, const float* __restrict__ router,
    int* __restrict__ cnt, int* __restrict__ list, ushort* __restrict__ xbf)
{
    const int t = blockIdx.x;
    const int tid = threadIdx.x;
    float4 xv = reinterpret_cast<const float4*>(x + (size_t)t * C_DIM)[tid];
    *reinterpret_cast<ushort4*>(xbf + (size_t)t * C_DIM + tid * 4) = f2bf4(xv);

    float p[E_NUM];
#pragma unroll
    for (int e = 0; e < E_NUM; e++) {
        float4 rv = reinterpret_cast<const float4*>(router + (size_t)e * C_DIM)[tid];
        p[e] = xv.x * rv.x + xv.y * rv.y + xv.z * rv.z + xv.w * rv.w;
    }
#pragma unroll
    for (int e = 0; e < E_NUM; e++) {
#pragma unroll
        for (int off = 32; off >= 1; off >>= 1)
            p[e] += __shfl_down(p[e], off, 64);
    }
    __shared__ float red[E_NUM][4];
    const int lane = tid & 63, wv = tid >> 6;
    if (lane == 0) {
#pragma unroll
        for (int e = 0; e < E_NUM; e++) red[e][wv] = p[e];
    }
    __syncthreads();
    if (tid == 0) {
        float best = -3.4e38f; int bi = 0;
#pragma unroll
        for (int e = 0; e < E_NUM; e++) {
            float v = red[e][0] + red[e][1] + red[e][2] + red[e][3];
            if (v > best) { best = v; bi = e; }
        }
        int pos = atomicAdd(&cnt[bi], 1);
        list[bi * T_TOK + pos] = t;
    }
}

// ug: BM=32 tokens x BN=16 h-rows, K=1024 in 4 chunks of 256 f32.
// Weights: page-linear global reads (1KB contiguous of ONE row per instr)
// -> regs -> bf16 -> XOR-swizzled ds_write. x: gload_lds, pre-swizzled src.
// 4 waves split K (64 f32 each per chunk); final LDS reduce + silu.
// grid (9 [8=shared], H/16=128, 8 token-tiles), block 256.
__global__ __launch_bounds__(256, 2) void ug_mfma(
    const ushort* __restrict__ xbf, const float* __restrict__ up, const float* __restrict__ gate,
    const float* __restrict__ w_up_s, const float* __restrict__ w_gate_s,
    const int* __restrict__ cnt, const int* __restrict__ list,
    ushort* __restrict__ hbuf, ushort* __restrict__ hsbuf)
{
    const int e = blockIdx.x, by = blockIdx.y, tt = blockIdx.z;
    const bool sh = (e == E_NUM);
    const int n = sh ? T_TOK : cnt[e];
    if (tt * 32 >= n) return;
    const int tid = threadIdx.x, lane = tid & 63, wv = tid >> 6;
    const int lc = lane & 15, kg = lane >> 4;

    __shared__ __align__(16) char smem[65536];
    ushort* Xl  = (ushort*)smem;                 // 2 bufs x 32 rows x 256 ush (32 KB)
    ushort* WuL = (ushort*)(smem + 32768);       // 2 bufs x 16 rows x 256 ush (16 KB)
    ushort* WgL = (ushort*)(smem + 49152);       // 16 KB
    __shared__ int toks_s[32];

    if (tid < 32) {
        int t = tt * 32 + tid;
        toks_s[tid] = (t < n) ? (sh ? t : list[e * T_TOK + t]) : -1;
    }
    __syncthreads();

    const int h0 = by * 16;
    const float* __restrict__ ubase = (sh ? w_up_s   : up   + (size_t)e * H_DIM * C_DIM) + (size_t)h0 * C_DIM;
    const float* __restrict__ gbase = (sh ? w_gate_s : gate + (size_t)e * H_DIM * C_DIM) + (size_t)h0 * C_DIM;

    float4 wreg[8];
    // 8 loads/wave: i<4 -> Wu row wv*4+i, i>=4 -> Wg row wv*4+(i-4).
    // Each instr: 1KB contiguous of one 4KB row-page.
#define W_LOAD(tc) do { _Pragma("unroll") for (int i = 0; i < 8; i++) { \
        int row_ = wv * 4 + (i & 3); \
        const float* b_ = (i < 4) ? ubase : gbase; \
        wreg[i] = *reinterpret_cast<const float4*>(b_ + (size_t)row_ * C_DIM + (tc) * 256 + lane * 4); \
    } } while (0)

    // lane holds f32 [lane*4,lane*4+4) of row-chunk -> kunit lane>>1, half lane&1
#define W_WRITE(bf) do { _Pragma("unroll") for (int i = 0; i < 8; i++) { \
        int row_ = wv * 4 + (i & 3); \
        ushort* WL_ = (i < 4) ? WuL : WgL; \
        int pos_ = ((lane >> 1) & ~7) | (((lane >> 1) ^ row_) & 7); \
        *reinterpret_cast<ushort4*>(WL_ + (bf) * 4096 + row_ * 256 + pos_ * 8 + (lane & 1) * 4) = f2bf4(wreg[i]); \
    } } while (0)

    // x: 4 gloads/wave; instr j covers rows 2j,2j+1 (512B each), src pre-swizzled
#define X_STAGE(tc, bf) do { _Pragma("unroll") for (int i = 0; i < 4; i++) { \
        int j_ = wv * 4 + i; \
        int row_ = 2 * j_ + (lane >> 5); \
        int p_ = lane & 31; \
        int su_ = (p_ & ~7) | ((p_ ^ row_) & 7); \
        int tok_ = toks_s[row_]; if (tok_ < 0) tok_ = 0; \
        gload16(xbf + (size_t)tok_ * C_DIM + (tc) * 256 + su_ * 8, (void*)(Xl + (bf) * 8192 + j_ * 512)); \
    } } while (0)

    f32x4 au0 = {0,0,0,0}, au1 = {0,0,0,0}, ag0 = {0,0,0,0}, ag1 = {0,0,0,0};
#define COMPUTE(bf) do { _Pragma("unroll") for (int k32 = 0; k32 < 2; k32++) { \
        int ku_ = wv * 8 + k32 * 4 + kg; \
        int up_ = (ku_ & ~7) | ((ku_ ^ lc) & 7); \
        short8 a0_ = *reinterpret_cast<const short8*>(Xl + (bf) * 8192 + lc * 256 + up_ * 8); \
        short8 a1_ = *reinterpret_cast<const short8*>(Xl + (bf) * 8192 + (16 + lc) * 256 + up_ * 8); \
        short8 bu_ = *reinterpret_cast<const short8*>(WuL + (bf) * 4096 + lc * 256 + up_ * 8); \
        short8 bg_ = *reinterpret_cast<const short8*>(WgL + (bf) * 4096 + lc * 256 + up_ * 8); \
        au0 = MFMA(a0_, bu_, au0); au1 = MFMA(a1_, bu_, au1); \
        ag0 = MFMA(a0_, bg_, ag0); ag1 = MFMA(a1_, bg_, ag1); \
    } } while (0)

    // prologue
    W_LOAD(0);            // vm 8
    X_STAGE(0, 0);        // vm 12
    VMWAIT(4);            // W0 regs ready
    W_WRITE(0);
    W_LOAD(1);            // vm <= 12
    X_STAGE(1, 1);        // vm <= 16
    LGKWAIT();
    VMWAIT(12);           // X0 landed (W1+X1 in flight)
    BAR();

#pragma unroll
    for (int t = 0; t < 4; t++) {
        COMPUTE(t & 1);
        if (t < 3) {
            VMWAIT(4);                 // W(t+1) regs ready; X(t+1) in flight
            W_WRITE((t + 1) & 1);
            if (t < 2) W_LOAD(t + 2);
            LGKWAIT();
        }
        BAR();                         // all done reading buf(t&1)
        if (t < 2) X_STAGE(t + 2, t & 1);
        if (t < 2)      { VMWAIT(12); }   // X(t+1) landed; W(t+2)+X(t+2) fly
        else if (t == 2){ VMWAIT(0);  }   // X(3) landed
        BAR();
    }

    // epilogue: cross-wave K reduce (alias buf0 of Xl) + silu + store
    f32x4* red = (f32x4*)smem;           // [4 wv][4 frag][64 lane] = 16 KB
    red[(wv * 4 + 0) * 64 + lane] = au0;
    red[(wv * 4 + 1) * 64 + lane] = au1;
    red[(wv * 4 + 2) * 64 + lane] = ag0;
    red[(wv * 4 + 3) * 64 + lane] = ag1;
    __syncthreads();
    if (tid < 128) {
        const int m = tid >> 6, ln = tid & 63, lc_ = ln & 15, kg_ = ln >> 4;
        f32x4 su = red[(0 + m) * 64 + ln];
        su += red[(4 + m) * 64 + ln];
        su += red[(8 + m) * 64 + ln];
        su += red[(12 + m) * 64 + ln];
        f32x4 sg = red[(2 + m) * 64 + ln];
        sg += red[(6 + m) * 64 + ln];
        sg += red[(10 + m) * 64 + ln];
        sg += red[(14 + m) * 64 + ln];
        ushort* __restrict__ outp = sh ? hsbuf : hbuf;
#pragma unroll
        for (int j = 0; j < 4; j++) {
            int tok = toks_s[m * 16 + kg_ * 4 + j];
            if (tok >= 0) {
                float g = sg[j], u = su[j];
                outp[(size_t)tok * H_DIM + h0 + lc_] = f2bf(u * (g / (1.f + __expf(-g))));
            }
        }
    }
#undef W_LOAD
#undef W_WRITE
#undef X_STAGE
#undef COMPUTE
}

// down: BM=32 tokens x BN=16 c-rows, K=2048 in 8 chunks of 256 f32.
// Same structure; W rows are 8KB pages. grid (9, C/16=64, 8), block 256.
__global__ __launch_bounds__(256, 2) void down_mfma(
    const float* __restrict__ dwn, const float* __restrict__ w_down_s,
    const ushort* __restrict__ hbuf, const ushort* __restrict__ hsbuf,
    const int* __restrict__ cnt, const int* __restrict__ list,
    float* __restrict__ y, float* __restrict__ yspart)
{
    const int e = blockIdx.x, by = blockIdx.y, tt = blockIdx.z;
    const bool sh = (e == E_NUM);
    const int n = sh ? T_TOK : cnt[e];
    if (tt * 32 >= n) return;
    const int tid = threadIdx.x, lane = tid & 63, wv = tid >> 6;
    const int lc = lane & 15, kg = lane >> 4;

    __shared__ __align__(16) char smem[49152];
    ushort* Hl  = (ushort*)smem;                 // 2 bufs x 32 rows x 256 ush (32 KB)
    ushort* WdL = (ushort*)(smem + 32768);       // 2 bufs x 16 rows x 256 ush (16 KB)
    __shared__ int toks_s[32];

    if (tid < 32) {
        int t = tt * 32 + tid;
        toks_s[tid] = (t < n) ? (sh ? t : list[e * T_TOK + t]) : -1;
    }
    __syncthreads();

    const int c0 = by * 16;
    const float* __restrict__ dbase = (sh ? w_down_s : dwn + (size_t)e * C_DIM * H_DIM) + (size_t)c0 * H_DIM;
    const ushort* __restrict__ hin = sh ? hsbuf : hbuf;

    float4 wreg[4];
#define W_LOAD(tc) do { _Pragma("unroll") for (int i = 0; i < 4; i++) { \
        int row_ = wv * 4 + i; \
        wreg[i] = *reinterpret_cast<const float4*>(dbase + (size_t)row_ * H_DIM + (tc) * 256 + lane * 4); \
    } } while (0)

#define W_WRITE(bf) do { _Pragma("unroll") for (int i = 0; i < 4; i++) { \
        int row_ = wv * 4 + i; \
        int pos_ = ((lane >> 1) & ~7) | (((lane >> 1) ^ row_) & 7); \
        *reinterpret_cast<ushort4*>(WdL + (bf) * 4096 + row_ * 256 + pos_ * 8 + (lane & 1) * 4) = f2bf4(wreg[i]); \
    } } while (0)

#define H_STAGE(tc, bf) do { _Pragma("unroll") for (int i = 0; i < 4; i++) { \
        int j_ = wv * 4 + i; \
        int row_ = 2 * j_ + (lane >> 5); \
        int p_ = lane & 31; \
        int su_ = (p_ & ~7) | ((p_ ^ row_) & 7); \
        int tok_ = toks_s[row_]; if (tok_ < 0) tok_ = 0; \
        gload16(hin + (size_t)tok_ * H_DIM + (tc) * 256 + su_ * 8, (void*)(Hl + (bf) * 8192 + j_ * 512)); \
    } } while (0)

    f32x4 ac0 = {0,0,0,0}, ac1 = {0,0,0,0};
#define COMPUTE(bf) do { _Pragma("unroll") for (int k32 = 0; k32 < 2; k32++) { \
        int ku_ = wv * 8 + k32 * 4 + kg; \
        int up_ = (ku_ & ~7) | ((ku_ ^ lc) & 7); \
        short8 a0_ = *reinterpret_cast<const short8*>(Hl + (bf) * 8192 + lc * 256 + up_ * 8); \
        short8 a1_ = *reinterpret_cast<const short8*>(Hl + (bf) * 8192 + (16 + lc) * 256 + up_ * 8); \
        short8 bd_ = *reinterpret_cast<const short8*>(WdL + (bf) * 4096 + lc * 256 + up_ * 8); \
        ac0 = MFMA(a0_, bd_, ac0); ac1 = MFMA(a1_, bd_, ac1); \
    } } while (0)

    // prologue
    W_LOAD(0);            // vm 4
    H_STAGE(0, 0);        // vm 8
    VMWAIT(4);            // W0 ready
    W_WRITE(0);
    W_LOAD(1);            // vm <= 8
    H_STAGE(1, 1);        // vm <= 12
    LGKWAIT();
    VMWAIT(8);            // H0 landed (W1+H1 fly)
    BAR();

#pragma unroll
    for (int t = 0; t < 8; t++) {
        COMPUTE(t & 1);
        if (t < 7) {
            VMWAIT(4);
            W_WRITE((t + 1) & 1);
            if (t < 6) W_LOAD(t + 2);
            LGKWAIT();
        }
        BAR();
        if (t < 6) H_STAGE(t + 2, t & 1);
        if (t < 6)      { VMWAIT(8); }
        else if (t == 6){ VMWAIT(0); }
        BAR();
    }

    // epilogue: reduce over 4 waves (alias buf0 of Hl, 8 KB) + store
    f32x4* red = (f32x4*)smem;           // [4 wv][2 frag][64 lane]
    red[(wv * 2 + 0) * 64 + lane] = ac0;
    red[(wv * 2 + 1) * 64 + lane] = ac1;
    __syncthreads();
    if (tid < 128) {
        const int m = tid >> 6, ln = tid & 63, lc_ = ln & 15, kg_ = ln >> 4;
        f32x4 s = red[(0 + m) * 64 + ln];
        s += red[(2 + m) * 64 + ln];
        s += red[(4 + m) * 64 + ln];
        s += red[(6 + m) * 64 + ln];
        float* __restrict__ outp = sh ? yspart : y;
#pragma unroll
        for (int j = 0; j < 4; j++) {
            int tok = toks_s[m * 16 + kg_ * 4 + j];
            if (tok >= 0) outp[(size_t)tok * C_DIM + c0 + lc_] = s[j];
        }
    }
#undef W_LOAD
#undef W_WRITE
#undef H_STAGE
#undef COMPUTE
}

__global__ __launch_bounds__(256) void add_kernel(float* __restrict__ y, const float* __restrict__ ys)
{
    int i = blockIdx.x * 256 + threadIdx.x;
    float4 a = reinterpret_cast<float4*>(y)[i];
    float4 b = reinterpret_cast<const float4*>(ys)[i];
    a.x += b.x; a.y += b.y; a.z += b.z; a.w += b.w;
    reinterpret_cast<float4*>(y)[i] = a;
}

extern "C" void kernel_launch(void* const* d_in, const int* in_sizes, int n_in,
                              void* d_out, int out_size, void* d_ws, size_t ws_size,
                              hipStream_t stream)
{
    const float* x        = (const float*)d_in[0];
    const float* up       = (const float*)d_in[1];
    const float* gate     = (const float*)d_in[2];
    const float* dwn      = (const float*)d_in[3];
    const float* router   = (const float*)d_in[4];
    const float* w_up_s   = (const float*)d_in[5];
    const float* w_gate_s = (const float*)d_in[6];
    const float* w_down_s = (const float*)d_in[7];

    char* ws = (char*)d_ws;
    int* cnt      = (int*)(ws + WS_CNT);
    int* list     = (int*)(ws + WS_LIST);
    ushort* xbf   = (ushort*)(ws + WS_XBF);
    ushort* hbuf  = (ushort*)(ws + WS_HBUF);
    ushort* hsbuf = (ushort*)(ws + WS_HSBUF);
    float* yspart = (float*)(ws + WS_YS);
    float* y = (float*)d_out;

    hipMemsetAsync(cnt, 0, E_NUM * sizeof(int), stream);
    router_kernel<<<T_TOK, 256, 0, stream>>>(x, router, cnt, list, xbf);
    ug_mfma<<<dim3(E_NUM + 1, H_DIM / 16, 8), 256, 0, stream>>>(
        xbf, up, gate, w_up_s, w_gate_s, cnt, list, hbuf, hsbuf);
    down_mfma<<<dim3(E_NUM + 1, C_DIM / 16, 8), 256, 0, stream>>>(
        dwn, w_down_s, hbuf, hsbuf, cnt, list, y, yspart);
    add_kernel<<<(T_TOK * C_DIM / 4) / 256, 256, 0, stream>>>(y, yspart);
}

// Round 12
// 90.676 us; speedup vs baseline: 1.3104x; 1.0208x over previous
//
#include <hip/hip_runtime.h>
#include <hip/hip_bf16.h>

#define T_TOK 256
#define C_DIM 1024
#define H_DIM 2048
#define E_NUM 8

typedef __attribute__((ext_vector_type(4))) float f32x4;
typedef __attribute__((ext_vector_type(8))) short short8;

// workspace layout (bytes)
#define WS_CNT    0
#define WS_LIST   1024
#define WS_XBF    16384                      // 256*1024*2 = 512 KB
#define WS_HBUF   (1u<<20)                   // 1 MB bf16 (expert h)
#define WS_HSBUF  (2u<<20)                   // 1 MB bf16 (shared h)
#define WS_YS     (3u<<20)                   // 1 MB f32 (shared y)

__device__ __forceinline__ ushort f2bf(float f) {
    __hip_bfloat16 h = __float2bfloat16(f);
    return *reinterpret_cast<ushort*>(&h);
}

__device__ __forceinline__ ushort4 f2bf4(float4 v) {
    ushort4 r; r.x = f2bf(v.x); r.y = f2bf(v.y); r.z = f2bf(v.z); r.w = f2bf(v.w);
    return r;
}

__device__ __forceinline__ ushort4 f2bf4v(f32x4 v) {
    ushort4 r; r.x = f2bf(v[0]); r.y = f2bf(v[1]); r.z = f2bf(v[2]); r.w = f2bf(v[3]);
    return r;
}

// async global->LDS DMA, 16B/lane. LDS dest = wave-uniform base + lane*16.
__device__ __forceinline__ void gload16(const void* g, void* l) {
    __builtin_amdgcn_global_load_lds((const __attribute__((address_space(1))) void*)g,
                                     (__attribute__((address_space(3))) void*)l, 16, 0, 0);
}

#define MFMA(a, b, c) __builtin_amdgcn_mfma_f32_16x16x32_bf16((a), (b), (c), 0, 0, 0)

#define VMWAIT(N) do { asm volatile("s_waitcnt vmcnt(" #N ")" ::: "memory"); \
                       __builtin_amdgcn_sched_barrier(0); } while (0)
#define LGKWAIT() do { asm volatile("s_waitcnt lgkmcnt(0)" ::: "memory"); \
                       __builtin_amdgcn_sched_barrier(0); } while (0)
#define BAR() do { __builtin_amdgcn_s_barrier(); \
                   __builtin_amdgcn_sched_barrier(0); } while (0)

// router + x->bf16 prep fused. 1 block per token.
__global__ __launch_bounds__(256) void router_kernel(
    const float* __restrict__ x, const float* __restrict__ router,
    int* __restrict__ cnt, int* __restrict__ list, ushort* __restrict__ xbf)
{
    const int t = blockIdx.x;
    const int tid = threadIdx.x;
    float4 xv = reinterpret_cast<const float4*>(x + (size_t)t * C_DIM)[tid];
    *reinterpret_cast<ushort4*>(xbf + (size_t)t * C_DIM + tid * 4) = f2bf4(xv);

    float p[E_NUM];
#pragma unroll
    for (int e = 0; e < E_NUM; e++) {
        float4 rv = reinterpret_cast<const float4*>(router + (size_t)e * C_DIM)[tid];
        p[e] = xv.x * rv.x + xv.y * rv.y + xv.z * rv.z + xv.w * rv.w;
    }
#pragma unroll
    for (int e = 0; e < E_NUM; e++) {
#pragma unroll
        for (int off = 32; off >= 1; off >>= 1)
            p[e] += __shfl_down(p[e], off, 64);
    }
    __shared__ float red[E_NUM][4];
    const int lane = tid & 63, wv = tid >> 6;
    if (lane == 0) {
#pragma unroll
        for (int e = 0; e < E_NUM; e++) red[e][wv] = p[e];
    }
    __syncthreads();
    if (tid == 0) {
        float best = -3.4e38f; int bi = 0;
#pragma unroll
        for (int e = 0; e < E_NUM; e++) {
            float v = red[e][0] + red[e][1] + red[e][2] + red[e][3];
            if (v > best) { best = v; bi = e; }
        }
        int pos = atomicAdd(&cnt[bi], 1);
        list[bi * T_TOK + pos] = t;
    }
}

// ug: BM=32 tokens x BN=16 h-rows, K=1024 in 4 chunks of 256 f32.
// Expert weights: NON-TEMPORAL page-linear reads (1KB of one row per instr,
// no L3 pollution) -> regs -> bf16 -> swizzled ds_write. Shared weights:
// normal loads (stay L3-resident). x: gload_lds, pre-swizzled source.
// Sync: __syncthreads() only (compiler-managed waits — race-free by
// construction; R10's hand-counted vmcnt over mixed op classes raced).
// grid (9 [8=shared], H/16=128, 8 token-tiles), block 256, 32 KB LDS.
__global__ __launch_bounds__(256, 3) void ug_mfma(
    const ushort* __restrict__ xbf, const float* __restrict__ up, const float* __restrict__ gate,
    const float* __restrict__ w_up_s, const float* __restrict__ w_gate_s,
    const int* __restrict__ cnt, const int* __restrict__ list,
    ushort* __restrict__ hbuf, ushort* __restrict__ hsbuf)
{
    const int e = blockIdx.x, by = blockIdx.y, tt = blockIdx.z;
    const bool sh = (e == E_NUM);
    const int n = sh ? T_TOK : cnt[e];
    if (tt * 32 >= n) return;
    const int tid = threadIdx.x, lane = tid & 63, wv = tid >> 6;
    const int lc = lane & 15, kg = lane >> 4;

    __shared__ __align__(16) char smem[32768];
    ushort* Xl  = (ushort*)smem;                 // 16 KB: 32 rows x 256 ush
    ushort* WuL = (ushort*)(smem + 16384);       // 8 KB: 16 rows x 256 ush
    ushort* WgL = (ushort*)(smem + 24576);       // 8 KB
    __shared__ int toks_s[32];

    if (tid < 32) {
        int t = tt * 32 + tid;
        toks_s[tid] = (t < n) ? (sh ? t : list[e * T_TOK + t]) : -1;
    }
    __syncthreads();

    const int h0 = by * 16;
    const float* __restrict__ ubase = (sh ? w_up_s   : up   + (size_t)e * H_DIM * C_DIM) + (size_t)h0 * C_DIM;
    const float* __restrict__ gbase = (sh ? w_gate_s : gate + (size_t)e * H_DIM * C_DIM) + (size_t)h0 * C_DIM;

    f32x4 wreg[8];
    // 8 loads/wave: i<4 -> Wu row wv*4+i, i>=4 -> Wg. 1KB contiguous per instr.
#define W_LOAD(tc) do { _Pragma("unroll") for (int i = 0; i < 8; i++) { \
        int row_ = wv * 4 + (i & 3); \
        const float* b_ = (i < 4) ? ubase : gbase; \
        const f32x4* p_ = reinterpret_cast<const f32x4*>(b_ + (size_t)row_ * C_DIM + (tc) * 256 + lane * 4); \
        wreg[i] = sh ? *p_ : __builtin_nontemporal_load(p_); \
    } } while (0)

#define W_WRITE() do { _Pragma("unroll") for (int i = 0; i < 8; i++) { \
        int row_ = wv * 4 + (i & 3); \
        ushort* WL_ = (i < 4) ? WuL : WgL; \
        int pos_ = ((lane >> 1) & ~7) | (((lane >> 1) ^ row_) & 7); \
        *reinterpret_cast<ushort4*>(WL_ + row_ * 256 + pos_ * 8 + (lane & 1) * 4) = f2bf4v(wreg[i]); \
    } } while (0)

#define X_STAGE(tc) do { _Pragma("unroll") for (int i = 0; i < 4; i++) { \
        int j_ = wv * 4 + i; \
        int row_ = 2 * j_ + (lane >> 5); \
        int p_ = lane & 31; \
        int su_ = (p_ & ~7) | ((p_ ^ row_) & 7); \
        int tok_ = toks_s[row_]; if (tok_ < 0) tok_ = 0; \
        gload16(xbf + (size_t)tok_ * C_DIM + (tc) * 256 + su_ * 8, (void*)(Xl + j_ * 512)); \
    } } while (0)

    f32x4 au0 = {0,0,0,0}, au1 = {0,0,0,0}, ag0 = {0,0,0,0}, ag1 = {0,0,0,0};
#define COMPUTE() do { _Pragma("unroll") for (int k32 = 0; k32 < 2; k32++) { \
        int ku_ = wv * 8 + k32 * 4 + kg; \
        int up_ = (ku_ & ~7) | ((ku_ ^ lc) & 7); \
        short8 a0_ = *reinterpret_cast<const short8*>(Xl + lc * 256 + up_ * 8); \
        short8 a1_ = *reinterpret_cast<const short8*>(Xl + (16 + lc) * 256 + up_ * 8); \
        short8 bu_ = *reinterpret_cast<const short8*>(WuL + lc * 256 + up_ * 8); \
        short8 bg_ = *reinterpret_cast<const short8*>(WgL + lc * 256 + up_ * 8); \
        au0 = MFMA(a0_, bu_, au0); au1 = MFMA(a1_, bu_, au1); \
        ag0 = MFMA(a0_, bg_, ag0); ag1 = MFMA(a1_, bg_, ag1); \
    } } while (0)

    W_LOAD(0);
#pragma unroll
    for (int t = 0; t < 4; t++) {
        X_STAGE(t);                 // async into Xl (safe: past prev trailing barrier)
        W_WRITE();                  // compiler waits on wreg(t) loads, packs, ds_write
        if (t < 3) W_LOAD(t + 1);   // next W chunk issued; drains at the barrier
        __syncthreads();            // full drain: X + W writes visible to all waves
        COMPUTE();
        __syncthreads();            // all waves done reading Xl/WuL/WgL
    }
#undef W_LOAD
#undef W_WRITE
#undef X_STAGE
#undef COMPUTE

    // epilogue: cross-wave K reduce (alias Xl region) + silu + store
    f32x4* red = (f32x4*)smem;               // [4 wv][4 frag][64 lane] = 16 KB
    red[(wv * 4 + 0) * 64 + lane] = au0;
    red[(wv * 4 + 1) * 64 + lane] = au1;
    red[(wv * 4 + 2) * 64 + lane] = ag0;
    red[(wv * 4 + 3) * 64 + lane] = ag1;
    __syncthreads();
    if (tid < 128) {
        const int m = tid >> 6, ln = tid & 63, lc_ = ln & 15, kg_ = ln >> 4;
        f32x4 su = red[(0 + m) * 64 + ln];
        su += red[(4 + m) * 64 + ln];
        su += red[(8 + m) * 64 + ln];
        su += red[(12 + m) * 64 + ln];
        f32x4 sg = red[(2 + m) * 64 + ln];
        sg += red[(6 + m) * 64 + ln];
        sg += red[(10 + m) * 64 + ln];
        sg += red[(14 + m) * 64 + ln];
        ushort* __restrict__ outp = sh ? hsbuf : hbuf;
#pragma unroll
        for (int j = 0; j < 4; j++) {
            int tok = toks_s[m * 16 + kg_ * 4 + j];
            if (tok >= 0) {
                float g = sg[j], u = su[j];
                outp[(size_t)tok * H_DIM + h0 + lc_] = f2bf(u * (g / (1.f + __expf(-g))));
            }
        }
    }
}

// down: BM=32 tokens x BN=16 c-rows, K=2048 in 8 chunks of 256 f32.
// UNCHANGED from R9/R10 (passed twice; L3-hot ~5 us).
__global__ __launch_bounds__(256, 2) void down_mfma(
    const float* __restrict__ dwn, const float* __restrict__ w_down_s,
    const ushort* __restrict__ hbuf, const ushort* __restrict__ hsbuf,
    const int* __restrict__ cnt, const int* __restrict__ list,
    float* __restrict__ y, float* __restrict__ yspart)
{
    const int e = blockIdx.x, by = blockIdx.y, tt = blockIdx.z;
    const bool sh = (e == E_NUM);
    const int n = sh ? T_TOK : cnt[e];
    if (tt * 32 >= n) return;
    const int tid = threadIdx.x, lane = tid & 63, wv = tid >> 6;
    const int lc = lane & 15, kg = lane >> 4;

    __shared__ __align__(16) char smem[49152];
    ushort* Hl  = (ushort*)smem;                 // 2 bufs x 32 rows x 256 ush (32 KB)
    ushort* WdL = (ushort*)(smem + 32768);       // 2 bufs x 16 rows x 256 ush (16 KB)
    __shared__ int toks_s[32];

    if (tid < 32) {
        int t = tt * 32 + tid;
        toks_s[tid] = (t < n) ? (sh ? t : list[e * T_TOK + t]) : -1;
    }
    __syncthreads();

    const int c0 = by * 16;
    const float* __restrict__ dbase = (sh ? w_down_s : dwn + (size_t)e * C_DIM * H_DIM) + (size_t)c0 * H_DIM;
    const ushort* __restrict__ hin = sh ? hsbuf : hbuf;

    float4 wreg[4];
#define W_LOAD(tc) do { _Pragma("unroll") for (int i = 0; i < 4; i++) { \
        int row_ = wv * 4 + i; \
        wreg[i] = *reinterpret_cast<const float4*>(dbase + (size_t)row_ * H_DIM + (tc) * 256 + lane * 4); \
    } } while (0)

#define W_WRITE(bf) do { _Pragma("unroll") for (int i = 0; i < 4; i++) { \
        int row_ = wv * 4 + i; \
        int pos_ = ((lane >> 1) & ~7) | (((lane >> 1) ^ row_) & 7); \
        *reinterpret_cast<ushort4*>(WdL + (bf) * 4096 + row_ * 256 + pos_ * 8 + (lane & 1) * 4) = f2bf4(wreg[i]); \
    } } while (0)

#define H_STAGE(tc, bf) do { _Pragma("unroll") for (int i = 0; i < 4; i++) { \
        int j_ = wv * 4 + i; \
        int row_ = 2 * j_ + (lane >> 5); \
        int p_ = lane & 31; \
        int su_ = (p_ & ~7) | ((p_ ^ row_) & 7); \
        int tok_ = toks_s[row_]; if (tok_ < 0) tok_ = 0; \
        gload16(hin + (size_t)tok_ * H_DIM + (tc) * 256 + su_ * 8, (void*)(Hl + (bf) * 8192 + j_ * 512)); \
    } } while (0)

    f32x4 ac0 = {0,0,0,0}, ac1 = {0,0,0,0};
#define COMPUTE(bf) do { _Pragma("unroll") for (int k32 = 0; k32 < 2; k32++) { \
        int ku_ = wv * 8 + k32 * 4 + kg; \
        int up_ = (ku_ & ~7) | ((ku_ ^ lc) & 7); \
        short8 a0_ = *reinterpret_cast<const short8*>(Hl + (bf) * 8192 + lc * 256 + up_ * 8); \
        short8 a1_ = *reinterpret_cast<const short8*>(Hl + (bf) * 8192 + (16 + lc) * 256 + up_ * 8); \
        short8 bd_ = *reinterpret_cast<const short8*>(WdL + (bf) * 4096 + lc * 256 + up_ * 8); \
        ac0 = MFMA(a0_, bd_, ac0); ac1 = MFMA(a1_, bd_, ac1); \
    } } while (0)

    // prologue
    W_LOAD(0);            // vm 4
    H_STAGE(0, 0);        // vm 8
    VMWAIT(4);            // W0 ready
    W_WRITE(0);
    W_LOAD(1);            // vm <= 8
    H_STAGE(1, 1);        // vm <= 12
    LGKWAIT();
    VMWAIT(8);            // H0 landed (W1+H1 fly)
    BAR();

#pragma unroll
    for (int t = 0; t < 8; t++) {
        COMPUTE(t & 1);
        if (t < 7) {
            VMWAIT(4);
            W_WRITE((t + 1) & 1);
            if (t < 6) W_LOAD(t + 2);
            LGKWAIT();
        }
        BAR();
        if (t < 6) H_STAGE(t + 2, t & 1);
        if (t < 6)      { VMWAIT(8); }
        else if (t == 6){ VMWAIT(0); }
        BAR();
    }

    // epilogue: reduce over 4 waves (alias buf0 of Hl) + store
    f32x4* red = (f32x4*)smem;           // [4 wv][2 frag][64 lane]
    red[(wv * 2 + 0) * 64 + lane] = ac0;
    red[(wv * 2 + 1) * 64 + lane] = ac1;
    __syncthreads();
    if (tid < 128) {
        const int m = tid >> 6, ln = tid & 63, lc_ = ln & 15, kg_ = ln >> 4;
        f32x4 s = red[(0 + m) * 64 + ln];
        s += red[(2 + m) * 64 + ln];
        s += red[(4 + m) * 64 + ln];
        s += red[(6 + m) * 64 + ln];
        float* __restrict__ outp = sh ? yspart : y;
#pragma unroll
        for (int j = 0; j < 4; j++) {
            int tok = toks_s[m * 16 + kg_ * 4 + j];
            if (tok >= 0) outp[(size_t)tok * C_DIM + c0 + lc_] = s[j];
        }
    }
#undef W_LOAD
#undef W_WRITE
#undef H_STAGE
#undef COMPUTE
}

__global__ __launch_bounds__(256) void add_kernel(float* __restrict__ y, const float* __restrict__ ys)
{
    int i = blockIdx.x * 256 + threadIdx.x;
    float4 a = reinterpret_cast<float4*>(y)[i];
    float4 b = reinterpret_cast<const float4*>(ys)[i];
    a.x += b.x; a.y += b.y; a.z += b.z; a.w += b.w;
    reinterpret_cast<float4*>(y)[i] = a;
}

extern "C" void kernel_launch(void* const* d_in, const int* in_sizes, int n_in,
                              void* d_out, int out_size, void* d_ws, size_t ws_size,
                              hipStream_t stream)
{
    const float* x        = (const float*)d_in[0];
    const float* up       = (const float*)d_in[1];
    const float* gate     = (const float*)d_in[2];
    const float* dwn      = (const float*)d_in[3];
    const float* router   = (const float*)d_in[4];
    const float* w_up_s   = (const float*)d_in[5];
    const float* w_gate_s = (const float*)d_in[6];
    const float* w_down_s = (const float*)d_in[7];

    char* ws = (char*)d_ws;
    int* cnt      = (int*)(ws + WS_CNT);
    int* list     = (int*)(ws + WS_LIST);
    ushort* xbf   = (ushort*)(ws + WS_XBF);
    ushort* hbuf  = (ushort*)(ws + WS_HBUF);
    ushort* hsbuf = (ushort*)(ws + WS_HSBUF);
    float* yspart = (float*)(ws + WS_YS);
    float* y = (float*)d_out;

    hipMemsetAsync(cnt, 0, E_NUM * sizeof(int), stream);
    router_kernel<<<T_TOK, 256, 0, stream>>>(x, router, cnt, list, xbf);
    ug_mfma<<<dim3(E_NUM + 1, H_DIM / 16, 8), 256, 0, stream>>>(
        xbf, up, gate, w_up_s, w_gate_s, cnt, list, hbuf, hsbuf);
    down_mfma<<<dim3(E_NUM + 1, C_DIM / 16, 8), 256, 0, stream>>>(
        dwn, w_down_s, hbuf, hsbuf, cnt, list, y, yspart);
    add_kernel<<<(T_TOK * C_DIM / 4) / 256, 256, 0, stream>>>(y, yspart);
}

// Round 13
// 86.818 us; speedup vs baseline: 1.3687x; 1.0444x over previous
//
#include <hip/hip_runtime.h>
#include <hip/hip_bf16.h>

#define T_TOK 256
#define C_DIM 1024
#define H_DIM 2048
#define E_NUM 8

typedef __attribute__((ext_vector_type(4))) float f32x4;
typedef __attribute__((ext_vector_type(8))) short short8;

// workspace layout (bytes)
#define WS_CNT    0
#define WS_LIST   1024
#define WS_XBF    16384                      // 256*1024*2 = 512 KB
#define WS_HBUF   (1u<<20)                   // 1 MB bf16 (expert h)
#define WS_HSBUF  (2u<<20)                   // 1 MB bf16 (shared h)
#define WS_YS     (3u<<20)                   // 1 MB f32 (shared y)

__device__ __forceinline__ ushort f2bf(float f) {
    __hip_bfloat16 h = __float2bfloat16(f);
    return *reinterpret_cast<ushort*>(&h);
}

__device__ __forceinline__ ushort4 f2bf4(float4 v) {
    ushort4 r; r.x = f2bf(v.x); r.y = f2bf(v.y); r.z = f2bf(v.z); r.w = f2bf(v.w);
    return r;
}

__device__ __forceinline__ ushort4 f2bf4v(f32x4 v) {
    ushort4 r; r.x = f2bf(v[0]); r.y = f2bf(v[1]); r.z = f2bf(v[2]); r.w = f2bf(v[3]);
    return r;
}

// async global->LDS DMA, 16B/lane. LDS dest = wave-uniform base + lane*16.
__device__ __forceinline__ void gload16(const void* g, void* l) {
    __builtin_amdgcn_global_load_lds((const __attribute__((address_space(1))) void*)g,
                                     (__attribute__((address_space(3))) void*)l, 16, 0, 0);
}

#define MFMA(a, b, c) __builtin_amdgcn_mfma_f32_16x16x32_bf16((a), (b), (c), 0, 0, 0)

#define VMWAIT(N) do { asm volatile("s_waitcnt vmcnt(" #N ")" ::: "memory"); \
                       __builtin_amdgcn_sched_barrier(0); } while (0)
#define LGKWAIT() do { asm volatile("s_waitcnt lgkmcnt(0)" ::: "memory"); \
                       __builtin_amdgcn_sched_barrier(0); } while (0)
#define BAR() do { __builtin_amdgcn_s_barrier(); \
                   __builtin_amdgcn_sched_barrier(0); } while (0)

// router + x->bf16 prep fused. 1 block per token.
__global__ __launch_bounds__(256) void router_kernel(
    const float* __restrict__ x, const float* __restrict__ router,
    int* __restrict__ cnt, int* __restrict__ list, ushort* __restrict__ xbf)
{
    const int t = blockIdx.x;
    const int tid = threadIdx.x;
    float4 xv = reinterpret_cast<const float4*>(x + (size_t)t * C_DIM)[tid];
    *reinterpret_cast<ushort4*>(xbf + (size_t)t * C_DIM + tid * 4) = f2bf4(xv);

    float p[E_NUM];
#pragma unroll
    for (int e = 0; e < E_NUM; e++) {
        float4 rv = reinterpret_cast<const float4*>(router + (size_t)e * C_DIM)[tid];
        p[e] = xv.x * rv.x + xv.y * rv.y + xv.z * rv.z + xv.w * rv.w;
    }
#pragma unroll
    for (int e = 0; e < E_NUM; e++) {
#pragma unroll
        for (int off = 32; off >= 1; off >>= 1)
            p[e] += __shfl_down(p[e], off, 64);
    }
    __shared__ float red[E_NUM][4];
    const int lane = tid & 63, wv = tid >> 6;
    if (lane == 0) {
#pragma unroll
        for (int e = 0; e < E_NUM; e++) red[e][wv] = p[e];
    }
    __syncthreads();
    if (tid == 0) {
        float best = -3.4e38f; int bi = 0;
#pragma unroll
        for (int e = 0; e < E_NUM; e++) {
            float v = red[e][0] + red[e][1] + red[e][2] + red[e][3];
            if (v > best) { best = v; bi = e; }
        }
        int pos = atomicAdd(&cnt[bi], 1);
        list[bi * T_TOK + pos] = t;
    }
}

// ug: BM=32 tokens x BN=16 h-rows, K=1024 in 4 chunks of 256 f32.
// A/B vs R11: up = NORMAL loads (retainable in cache across replays);
// gate = NON-TEMPORAL (streamed; shrinks cached cyclic set by 64 MB so
// up+down+shared fit). Everything else identical to the passing R11.
// grid (9 [8=shared], H/16=128, 8 token-tiles), block 256, 32 KB LDS.
__global__ __launch_bounds__(256, 3) void ug_mfma(
    const ushort* __restrict__ xbf, const float* __restrict__ up, const float* __restrict__ gate,
    const float* __restrict__ w_up_s, const float* __restrict__ w_gate_s,
    const int* __restrict__ cnt, const int* __restrict__ list,
    ushort* __restrict__ hbuf, ushort* __restrict__ hsbuf)
{
    const int e = blockIdx.x, by = blockIdx.y, tt = blockIdx.z;
    const bool sh = (e == E_NUM);
    const int n = sh ? T_TOK : cnt[e];
    if (tt * 32 >= n) return;
    const int tid = threadIdx.x, lane = tid & 63, wv = tid >> 6;
    const int lc = lane & 15, kg = lane >> 4;

    __shared__ __align__(16) char smem[32768];
    ushort* Xl  = (ushort*)smem;                 // 16 KB: 32 rows x 256 ush
    ushort* WuL = (ushort*)(smem + 16384);       // 8 KB: 16 rows x 256 ush
    ushort* WgL = (ushort*)(smem + 24576);       // 8 KB
    __shared__ int toks_s[32];

    if (tid < 32) {
        int t = tt * 32 + tid;
        toks_s[tid] = (t < n) ? (sh ? t : list[e * T_TOK + t]) : -1;
    }
    __syncthreads();

    const int h0 = by * 16;
    const float* __restrict__ ubase = (sh ? w_up_s   : up   + (size_t)e * H_DIM * C_DIM) + (size_t)h0 * C_DIM;
    const float* __restrict__ gbase = (sh ? w_gate_s : gate + (size_t)e * H_DIM * C_DIM) + (size_t)h0 * C_DIM;

    f32x4 wreg[8];
    // 8 loads/wave: i<4 -> Wu row wv*4+i (NORMAL: cacheable), i>=4 -> Wg
    // (NON-TEMPORAL: streamed, no cache pollution). 1KB contiguous per instr.
#define W_LOAD(tc) do { _Pragma("unroll") for (int i = 0; i < 8; i++) { \
        int row_ = wv * 4 + (i & 3); \
        const float* b_ = (i < 4) ? ubase : gbase; \
        const f32x4* p_ = reinterpret_cast<const f32x4*>(b_ + (size_t)row_ * C_DIM + (tc) * 256 + lane * 4); \
        wreg[i] = (sh || i < 4) ? *p_ : __builtin_nontemporal_load(p_); \
    } } while (0)

#define W_WRITE() do { _Pragma("unroll") for (int i = 0; i < 8; i++) { \
        int row_ = wv * 4 + (i & 3); \
        ushort* WL_ = (i < 4) ? WuL : WgL; \
        int pos_ = ((lane >> 1) & ~7) | (((lane >> 1) ^ row_) & 7); \
        *reinterpret_cast<ushort4*>(WL_ + row_ * 256 + pos_ * 8 + (lane & 1) * 4) = f2bf4v(wreg[i]); \
    } } while (0)

#define X_STAGE(tc) do { _Pragma("unroll") for (int i = 0; i < 4; i++) { \
        int j_ = wv * 4 + i; \
        int row_ = 2 * j_ + (lane >> 5); \
        int p_ = lane & 31; \
        int su_ = (p_ & ~7) | ((p_ ^ row_) & 7); \
        int tok_ = toks_s[row_]; if (tok_ < 0) tok_ = 0; \
        gload16(xbf + (size_t)tok_ * C_DIM + (tc) * 256 + su_ * 8, (void*)(Xl + j_ * 512)); \
    } } while (0)

    f32x4 au0 = {0,0,0,0}, au1 = {0,0,0,0}, ag0 = {0,0,0,0}, ag1 = {0,0,0,0};
#define COMPUTE() do { _Pragma("unroll") for (int k32 = 0; k32 < 2; k32++) { \
        int ku_ = wv * 8 + k32 * 4 + kg; \
        int up_ = (ku_ & ~7) | ((ku_ ^ lc) & 7); \
        short8 a0_ = *reinterpret_cast<const short8*>(Xl + lc * 256 + up_ * 8); \
        short8 a1_ = *reinterpret_cast<const short8*>(Xl + (16 + lc) * 256 + up_ * 8); \
        short8 bu_ = *reinterpret_cast<const short8*>(WuL + lc * 256 + up_ * 8); \
        short8 bg_ = *reinterpret_cast<const short8*>(WgL + lc * 256 + up_ * 8); \
        au0 = MFMA(a0_, bu_, au0); au1 = MFMA(a1_, bu_, au1); \
        ag0 = MFMA(a0_, bg_, ag0); ag1 = MFMA(a1_, bg_, ag1); \
    } } while (0)

    W_LOAD(0);
#pragma unroll
    for (int t = 0; t < 4; t++) {
        X_STAGE(t);                 // async into Xl (safe: past prev trailing barrier)
        W_WRITE();                  // compiler waits on wreg(t) loads, packs, ds_write
        if (t < 3) W_LOAD(t + 1);   // next W chunk issued; drains at the barrier
        __syncthreads();            // full drain: X + W writes visible to all waves
        COMPUTE();
        __syncthreads();            // all waves done reading Xl/WuL/WgL
    }
#undef W_LOAD
#undef W_WRITE
#undef X_STAGE
#undef COMPUTE

    // epilogue: cross-wave K reduce (alias Xl region) + silu + store
    f32x4* red = (f32x4*)smem;               // [4 wv][4 frag][64 lane] = 16 KB
    red[(wv * 4 + 0) * 64 + lane] = au0;
    red[(wv * 4 + 1) * 64 + lane] = au1;
    red[(wv * 4 + 2) * 64 + lane] = ag0;
    red[(wv * 4 + 3) * 64 + lane] = ag1;
    __syncthreads();
    if (tid < 128) {
        const int m = tid >> 6, ln = tid & 63, lc_ = ln & 15, kg_ = ln >> 4;
        f32x4 su = red[(0 + m) * 64 + ln];
        su += red[(4 + m) * 64 + ln];
        su += red[(8 + m) * 64 + ln];
        su += red[(12 + m) * 64 + ln];
        f32x4 sg = red[(2 + m) * 64 + ln];
        sg += red[(6 + m) * 64 + ln];
        sg += red[(10 + m) * 64 + ln];
        sg += red[(14 + m) * 64 + ln];
        ushort* __restrict__ outp = sh ? hsbuf : hbuf;
#pragma unroll
        for (int j = 0; j < 4; j++) {
            int tok = toks_s[m * 16 + kg_ * 4 + j];
            if (tok >= 0) {
                float g = sg[j], u = su[j];
                outp[(size_t)tok * H_DIM + h0 + lc_] = f2bf(u * (g / (1.f + __expf(-g))));
            }
        }
    }
}

// down: BM=32 tokens x BN=16 c-rows, K=2048 in 8 chunks of 256 f32.
// UNCHANGED (passed three times; cache-served ~6 TB/s).
__global__ __launch_bounds__(256, 2) void down_mfma(
    const float* __restrict__ dwn, const float* __restrict__ w_down_s,
    const ushort* __restrict__ hbuf, const ushort* __restrict__ hsbuf,
    const int* __restrict__ cnt, const int* __restrict__ list,
    float* __restrict__ y, float* __restrict__ yspart)
{
    const int e = blockIdx.x, by = blockIdx.y, tt = blockIdx.z;
    const bool sh = (e == E_NUM);
    const int n = sh ? T_TOK : cnt[e];
    if (tt * 32 >= n) return;
    const int tid = threadIdx.x, lane = tid & 63, wv = tid >> 6;
    const int lc = lane & 15, kg = lane >> 4;

    __shared__ __align__(16) char smem[49152];
    ushort* Hl  = (ushort*)smem;                 // 2 bufs x 32 rows x 256 ush (32 KB)
    ushort* WdL = (ushort*)(smem + 32768);       // 2 bufs x 16 rows x 256 ush (16 KB)
    __shared__ int toks_s[32];

    if (tid < 32) {
        int t = tt * 32 + tid;
        toks_s[tid] = (t < n) ? (sh ? t : list[e * T_TOK + t]) : -1;
    }
    __syncthreads();

    const int c0 = by * 16;
    const float* __restrict__ dbase = (sh ? w_down_s : dwn + (size_t)e * C_DIM * H_DIM) + (size_t)c0 * H_DIM;
    const ushort* __restrict__ hin = sh ? hsbuf : hbuf;

    float4 wreg[4];
#define W_LOAD(tc) do { _Pragma("unroll") for (int i = 0; i < 4; i++) { \
        int row_ = wv * 4 + i; \
        wreg[i] = *reinterpret_cast<const float4*>(dbase + (size_t)row_ * H_DIM + (tc) * 256 + lane * 4); \
    } } while (0)

#define W_WRITE(bf) do { _Pragma("unroll") for (int i = 0; i < 4; i++) { \
        int row_ = wv * 4 + i; \
        int pos_ = ((lane >> 1) & ~7) | (((lane >> 1) ^ row_) & 7); \
        *reinterpret_cast<ushort4*>(WdL + (bf) * 4096 + row_ * 256 + pos_ * 8 + (lane & 1) * 4) = f2bf4(wreg[i]); \
    } } while (0)

#define H_STAGE(tc, bf) do { _Pragma("unroll") for (int i = 0; i < 4; i++) { \
        int j_ = wv * 4 + i; \
        int row_ = 2 * j_ + (lane >> 5); \
        int p_ = lane & 31; \
        int su_ = (p_ & ~7) | ((p_ ^ row_) & 7); \
        int tok_ = toks_s[row_]; if (tok_ < 0) tok_ = 0; \
        gload16(hin + (size_t)tok_ * H_DIM + (tc) * 256 + su_ * 8, (void*)(Hl + (bf) * 8192 + j_ * 512)); \
    } } while (0)

    f32x4 ac0 = {0,0,0,0}, ac1 = {0,0,0,0};
#define COMPUTE(bf) do { _Pragma("unroll") for (int k32 = 0; k32 < 2; k32++) { \
        int ku_ = wv * 8 + k32 * 4 + kg; \
        int up_ = (ku_ & ~7) | ((ku_ ^ lc) & 7); \
        short8 a0_ = *reinterpret_cast<const short8*>(Hl + (bf) * 8192 + lc * 256 + up_ * 8); \
        short8 a1_ = *reinterpret_cast<const short8*>(Hl + (bf) * 8192 + (16 + lc) * 256 + up_ * 8); \
        short8 bd_ = *reinterpret_cast<const short8*>(WdL + (bf) * 4096 + lc * 256 + up_ * 8); \
        ac0 = MFMA(a0_, bd_, ac0); ac1 = MFMA(a1_, bd_, ac1); \
    } } while (0)

    // prologue
    W_LOAD(0);            // vm 4
    H_STAGE(0, 0);        // vm 8
    VMWAIT(4);            // W0 ready
    W_WRITE(0);
    W_LOAD(1);            // vm <= 8
    H_STAGE(1, 1);        // vm <= 12
    LGKWAIT();
    VMWAIT(8);            // H0 landed (W1+H1 fly)
    BAR();

#pragma unroll
    for (int t = 0; t < 8; t++) {
        COMPUTE(t & 1);
        if (t < 7) {
            VMWAIT(4);
            W_WRITE((t + 1) & 1);
            if (t < 6) W_LOAD(t + 2);
            LGKWAIT();
        }
        BAR();
        if (t < 6) H_STAGE(t + 2, t & 1);
        if (t < 6)      { VMWAIT(8); }
        else if (t == 6){ VMWAIT(0); }
        BAR();
    }

    // epilogue: reduce over 4 waves (alias buf0 of Hl) + store
    f32x4* red = (f32x4*)smem;           // [4 wv][2 frag][64 lane]
    red[(wv * 2 + 0) * 64 + lane] = ac0;
    red[(wv * 2 + 1) * 64 + lane] = ac1;
    __syncthreads();
    if (tid < 128) {
        const int m = tid >> 6, ln = tid & 63, lc_ = ln & 15, kg_ = ln >> 4;
        f32x4 s = red[(0 + m) * 64 + ln];
        s += red[(2 + m) * 64 + ln];
        s += red[(4 + m) * 64 + ln];
        s += red[(6 + m) * 64 + ln];
        float* __restrict__ outp = sh ? yspart : y;
#pragma unroll
        for (int j = 0; j < 4; j++) {
            int tok = toks_s[m * 16 + kg_ * 4 + j];
            if (tok >= 0) outp[(size_t)tok * C_DIM + c0 + lc_] = s[j];
        }
    }
#undef W_LOAD
#undef W_WRITE
#undef H_STAGE
#undef COMPUTE
}

__global__ __launch_bounds__(256) void add_kernel(float* __restrict__ y, const float* __restrict__ ys)
{
    int i = blockIdx.x * 256 + threadIdx.x;
    float4 a = reinterpret_cast<float4*>(y)[i];
    float4 b = reinterpret_cast<const float4*>(ys)[i];
    a.x += b.x; a.y += b.y; a.z += b.z; a.w += b.w;
    reinterpret_cast<float4*>(y)[i] = a;
}

extern "C" void kernel_launch(void* const* d_in, const int* in_sizes, int n_in,
                              void* d_out, int out_size, void* d_ws, size_t ws_size,
                              hipStream_t stream)
{
    const float* x        = (const float*)d_in[0];
    const float* up       = (const float*)d_in[1];
    const float* gate     = (const float*)d_in[2];
    const float* dwn      = (const float*)d_in[3];
    const float* router   = (const float*)d_in[4];
    const float* w_up_s   = (const float*)d_in[5];
    const float* w_gate_s = (const float*)d_in[6];
    const float* w_down_s = (const float*)d_in[7];

    char* ws = (char*)d_ws;
    int* cnt      = (int*)(ws + WS_CNT);
    int* list     = (int*)(ws + WS_LIST);
    ushort* xbf   = (ushort*)(ws + WS_XBF);
    ushort* hbuf  = (ushort*)(ws + WS_HBUF);
    ushort* hsbuf = (ushort*)(ws + WS_HSBUF);
    float* yspart = (float*)(ws + WS_YS);
    float* y = (float*)d_out;

    hipMemsetAsync(cnt, 0, E_NUM * sizeof(int), stream);
    router_kernel<<<T_TOK, 256, 0, stream>>>(x, router, cnt, list, xbf);
    ug_mfma<<<dim3(E_NUM + 1, H_DIM / 16, 8), 256, 0, stream>>>(
        xbf, up, gate, w_up_s, w_gate_s, cnt, list, hbuf, hsbuf);
    down_mfma<<<dim3(E_NUM + 1, C_DIM / 16, 8), 256, 0, stream>>>(
        dwn, w_down_s, hbuf, hsbuf, cnt, list, y, yspart);
    add_kernel<<<(T_TOK * C_DIM / 4) / 256, 256, 0, stream>>>(y, yspart);
}